// Round 10
// baseline (203.264 us; speedup 1.0000x reference)
//
#include <hip/hip_runtime.h>

#define BB 2
#define CC 1024
#define HH 16
#define TT 2048
#define SS 2048
#define LL 2048   // T == S
#define C2MASK 1442695.0f   // 1e6 * log2(e)

typedef unsigned short u16;
typedef unsigned int u32;
typedef __attribute__((ext_vector_type(8))) short short8;
typedef __attribute__((ext_vector_type(4))) float f32x4;
typedef __attribute__((ext_vector_type(4))) unsigned short us4;
typedef __attribute__((ext_vector_type(2))) unsigned int u32x2;
typedef __attribute__((ext_vector_type(4))) unsigned int u32x4;

__device__ __forceinline__ u16 f2bf(float f) {
    union { float f; unsigned int i; } x; x.f = f;
    unsigned int r = x.i + 0x7FFFu + ((x.i >> 16) & 1u);
    return (u16)(r >> 16);
}
__device__ __forceinline__ float exp2_hw(float x) {
    float r;
    asm("v_exp_f32 %0, %1" : "=v"(r) : "v"(x));
    return r;
}
__device__ __forceinline__ float max3f(float a, float b, float c) {
    float r;
    asm("v_max3_f32 %0, %1, %2, %3" : "=v"(r) : "v"(a), "v"(b), "v"(c));
    return r;
}
__device__ __forceinline__ u32 cvtpk_bf16(float lo, float hi) {
    u32 r;
    asm("v_cvt_pk_bf16_f32 %0, %1, %2" : "=v"(r) : "v"(lo), "v"(hi));
    return r;
}
// direct global->LDS, 16B per lane; LDS dest = wave-uniform base + lane*16
__device__ __forceinline__ void gload_lds16(const u16* g, u16* l) {
    __builtin_amdgcn_global_load_lds(
        (const __attribute__((address_space(1))) unsigned int*)g,
        (__attribute__((address_space(3))) unsigned int*)l, 16, 0, 0);
}

// ---------- prep: one-shot fp32->bf16 conversion (memory-bound, unchanged) ----------
__global__ __launch_bounds__(256) void prep(
    const float* __restrict__ target, const float* __restrict__ source,
    const float* __restrict__ smaskp,
    const float* __restrict__ Wq, const float* __restrict__ Wk, const float* __restrict__ Wv,
    u16* __restrict__ Wb, u16* __restrict__ Tt, u16* __restrict__ St,
    float* __restrict__ sbias, float* __restrict__ zrow)
{
    __shared__ float xs[64][65];   // +1 pad: 2-way (free) banks both phases
    const int tid = threadIdx.x;
    const int bid = blockIdx.x;

    if (bid < 2048) {
        const int img  = bid >> 9;          // 0,1: target b=0,1; 2,3: source b=0,1
        const int tile = bid & 511;
        const int ct = tile >> 5, lt = tile & 31;
        const int c0 = ct * 64, l0 = lt * 64;
        const float* src = ((img < 2) ? target : source) + (size_t)(img & 1) * CC * LL;
        u16* dst = ((img < 2) ? Tt : St) + (size_t)(img & 1) * LL * CC;

        const int i = tid >> 2, seg = (tid & 3) * 16;
        const float* g = src + (size_t)(c0 + i) * LL + l0 + seg;
        f32x4 a0 = *(const f32x4*)g;
        f32x4 a1 = *(const f32x4*)(g + 4);
        f32x4 a2 = *(const f32x4*)(g + 8);
        f32x4 a3 = *(const f32x4*)(g + 12);
#pragma unroll
        for (int j = 0; j < 4; j++) {
            xs[i][seg + j]      = a0[j];
            xs[i][seg + 4 + j]  = a1[j];
            xs[i][seg + 8 + j]  = a2[j];
            xs[i][seg + 12 + j] = a3[j];
        }
        __syncthreads();

        const int l = tid >> 2, cseg = (tid & 3) * 16;
        float f[16];
#pragma unroll
        for (int j = 0; j < 16; j++) f[j] = xs[cseg + j][l];
        u32x4 o0, o1;
#pragma unroll
        for (int k = 0; k < 4; k++) {
            o0[k] = cvtpk_bf16(f[2 * k], f[2 * k + 1]);
            o1[k] = cvtpk_bf16(f[8 + 2 * k], f[9 + 2 * k]);
        }
        u16* d = dst + (size_t)(l0 + l) * CC + c0 + cseg;
        *(u32x4*)d = o0;
        *(u32x4*)(d + 8) = o1;
    } else {
        const int wblk = bid - 2048;              // 0..1535; 512 blocks per matrix
        const size_t idx = (size_t)wblk * 2048 + tid * 8;
        const int m = (int)(idx >> 20);
        const size_t rem = idx & 1048575;
        const float* srcp = ((m == 0) ? Wq : (m == 1) ? Wk : Wv) + rem;
        f32x4 a = *(const f32x4*)srcp;
        f32x4 c = *(const f32x4*)(srcp + 4);
        u32x4 o;
        o[0] = cvtpk_bf16(a[0], a[1]); o[1] = cvtpk_bf16(a[2], a[3]);
        o[2] = cvtpk_bf16(c[0], c[1]); o[3] = cvtpk_bf16(c[2], c[3]);
        *(u32x4*)(Wb + ((size_t)m << 20) + rem) = o;

        if (wblk < 2) {   // fused: s-mask additive bias (log2 domain) + zeros row
            const int b = wblk;
            const float* sm = smaskp + (size_t)b * SS;
            float* sb = sbias + (size_t)b * SS;
            for (int s = tid; s < SS; s += 256) {
                sb[s] = (sm[s] > 0.5f) ? 0.0f : -C2MASK;
                if (b == 0) zrow[s] = 0.0f;
            }
        }
    }
}

// ---------- QKV GEMM: 256x256 tile, BK=64, 8-phase interleave (r7, unchanged) ----------
__global__ __launch_bounds__(512, 2) void qkv_gemm(
    const u16* __restrict__ Wb, const u16* __restrict__ Tt, const u16* __restrict__ St,
    const float* __restrict__ bq, const float* __restrict__ bk, const float* __restrict__ bv,
    const float* __restrict__ tmaskp,
    u16* __restrict__ Qb, u16* __restrict__ Kb, u16* __restrict__ Vb)
{
    __shared__ __align__(16) u16 As[2][16384];   // 256 rows x 64 k, swizzled chunks (32KB ea)
    __shared__ __align__(16) u16 Bs[2][16384];

    // XCD-locality swizzle: 192 blocks, 192%8==0 -> bijective, chunk 24
    const int orig = blockIdx.x;
    const int wg   = (orig & 7) * 24 + (orig >> 3);
    const int mT   = wg >> 4;          // 0..11
    const int nT   = wg & 15;          // 0..15
    const int m0 = mT * 256;           // row in stacked-W space [0,3072)
    const int n0 = nT * 256;           // col in l-space [0,4096)
    const int p  = m0 >> 10;           // 0:Q 1:K 2:V

    const u16* A  = Wb + (size_t)m0 * CC;
    const u16* Bx = ((p == 0) ? Tt : St) + (size_t)n0 * CC;
    const float* bias = (p == 0) ? bq : (p == 1) ? bk : bv;

    const int tid  = threadIdx.x;
    const int lane = tid & 63;
    const int wid  = tid >> 6;         // 0..7
    const int ln   = lane & 15;
    const int q    = lane >> 4;
    const int wm   = (wid >> 2) * 128; // 2 M-groups
    const int wn   = (wid & 3) * 64;   // 4 N-groups

    const u16* ag[4]; const u16* bg[4];
#pragma unroll
    for (int e = 0; e < 4; e++) {
        const int s = tid + e * 512;
        const int row = s >> 3;
        const int c = (s & 7) ^ (row & 7);
        ag[e] = A  + (size_t)row * CC + c * 8;
        bg[e] = Bx + (size_t)row * CC + c * 8;
    }
    const int lw = wid * 512;          // wave-uniform u16 LDS base within each 512-slot set

#define STG_A(buf, k0, e)  gload_lds16(ag[e] + (k0), &As[buf][(e) * 4096 + lw])
#define STG_B(buf, k0, e)  gload_lds16(bg[e] + (k0), &Bs[buf][(e) * 4096 + lw])

    f32x4 acc[8][4];
#pragma unroll
    for (int i = 0; i < 8; i++)
#pragma unroll
        for (int j = 0; j < 4; j++) acc[i][j] = (f32x4){0.f, 0.f, 0.f, 0.f};

    const int sx0 = ((q ^ (ln & 7)) << 3);
    const int sx1 = (((q + 4) ^ (ln & 7)) << 3);

    short8 aQ[4][2];        // current A-quadrant
    short8 bQ[2][2][2];     // both B-quadrants [ntg][nti][kk]

#define PH_READ_A(cb, base_mt) do {                                        \
    _Pragma("unroll") for (int mt = 0; mt < 4; mt++) {                     \
        const u16* ar = &As[cb][(wm + ((base_mt) + mt) * 16 + ln) * 64];   \
        aQ[mt][0] = *(const short8*)(ar + sx0);                            \
        aQ[mt][1] = *(const short8*)(ar + sx1); } } while (0)
#define PH_READ_B(cb, ntg) do {                                            \
    _Pragma("unroll") for (int nt = 0; nt < 2; nt++) {                     \
        const u16* br = &Bs[cb][(wn + ((ntg) * 2 + nt) * 16 + ln) * 64];   \
        bQ[ntg][nt][0] = *(const short8*)(br + sx0);                       \
        bQ[ntg][nt][1] = *(const short8*)(br + sx1); } } while (0)
#define PH_MFMA(mbase, ntg) do {                                           \
    __builtin_amdgcn_s_setprio(1);                                         \
    _Pragma("unroll") for (int mt = 0; mt < 4; mt++)                       \
    _Pragma("unroll") for (int nt = 0; nt < 2; nt++) {                     \
        acc[(mbase) + mt][(ntg) * 2 + nt] = __builtin_amdgcn_mfma_f32_16x16x32_bf16( \
            aQ[mt][0], bQ[ntg][nt][0], acc[(mbase) + mt][(ntg) * 2 + nt], 0, 0, 0);  \
        acc[(mbase) + mt][(ntg) * 2 + nt] = __builtin_amdgcn_mfma_f32_16x16x32_bf16( \
            aQ[mt][1], bQ[ntg][nt][1], acc[(mbase) + mt][(ntg) * 2 + nt], 0, 0, 0); } \
    __builtin_amdgcn_s_setprio(0); } while (0)
#define LGKM0 do { asm volatile("s_waitcnt lgkmcnt(0)" ::: "memory");      \
                   __builtin_amdgcn_sched_barrier(0); } while (0)
#define VMDRAIN do { asm volatile("s_waitcnt vmcnt(0)" ::: "memory");      \
                     __builtin_amdgcn_sched_barrier(0); } while (0)

    // prologue: tile 0 -> buf0; __syncthreads drains vmcnt and publishes it
    STG_A(0, 0, 0); STG_A(0, 0, 1); STG_A(0, 0, 2); STG_A(0, 0, 3);
    STG_B(0, 0, 0); STG_B(0, 0, 1); STG_B(0, 0, 2); STG_B(0, 0, 3);
    __syncthreads();

#pragma unroll 1
    for (int T = 0; T < 16; ++T) {
        const int c  = T & 1;
        const int kn = (T + 1) * 64;
        const bool stg = (T < 15);

        // ph0: A-quad0 + B-quad0 | stage next-tile A
        PH_READ_A(c, 0); PH_READ_B(c, 0);
        if (stg) { STG_A(c ^ 1, kn, 0); STG_A(c ^ 1, kn, 1);
                   STG_A(c ^ 1, kn, 2); STG_A(c ^ 1, kn, 3); }
        __builtin_amdgcn_s_barrier(); LGKM0; PH_MFMA(0, 0);
        __builtin_amdgcn_s_barrier();

        // ph1: B-quad1 | stage next-tile B
        PH_READ_B(c, 1);
        if (stg) { STG_B(c ^ 1, kn, 0); STG_B(c ^ 1, kn, 1);
                   STG_B(c ^ 1, kn, 2); STG_B(c ^ 1, kn, 3); }
        __builtin_amdgcn_s_barrier(); LGKM0; PH_MFMA(0, 1);
        __builtin_amdgcn_s_barrier();

        // ph2: A-quad1
        PH_READ_A(c, 4);
        __builtin_amdgcn_s_barrier(); LGKM0; PH_MFMA(4, 0);
        __builtin_amdgcn_s_barrier();

        // ph3: pure MFMA; then race-free gate BEFORE the closing barrier
        PH_MFMA(4, 1);
        VMDRAIN;
        __builtin_amdgcn_s_barrier();
    }
#undef VMDRAIN
#undef LGKM0
#undef PH_MFMA
#undef PH_READ_B
#undef PH_READ_A
#undef STG_B
#undef STG_A

    // Q folds 1/sqrt(DH)*log2e and tmask (zeroed rows -> uniform softmax in attn)
    const float oscale = 0.18033688011112042f;
    // D layout: col = lane&15 (= l), row = q*4+reg (= o)
#pragma unroll
    for (int mt = 0; mt < 8; mt++) {
        const int o_base = (m0 & 1023) + wm + mt * 16 + q * 4;   // within-p output row
        float bsf[4];
#pragma unroll
        for (int r = 0; r < 4; r++) bsf[r] = bias[o_base + r];
#pragma unroll
        for (int nt = 0; nt < 4; nt++) {
            const int l  = n0 + wn + nt * 16 + ln;   // 0..4095
            const int b  = l >> 11;
            const int tk = l & 2047;
            if (p == 2) {
#pragma unroll
                for (int r = 0; r < 4; r++)
                    Vb[((size_t)b * CC + o_base + r) * SS + tk] = f2bf(acc[mt][nt][r] + bsf[r]);
            } else {
                const int h = o_base >> 6;
                const int d = o_base & 63;
                u16* dst = (p == 0) ? Qb : Kb;
                float sc2 = 1.0f;
                if (p == 0) sc2 = oscale * tmaskp[(size_t)b * TT + tk];
                us4 pk;
#pragma unroll
                for (int r = 0; r < 4; r++) pk[r] = (u16)f2bf((acc[mt][nt][r] + bsf[r]) * sc2);
                *(us4*)(dst + ((size_t)(b * HH + h) * TT + tk) * 64 + d) = pk;
            }
        }
    }
}

// ---------- flash attention: 8 waves, t=128/block, KVBLK=128, V halves ----------
// r9 structure + bias REGISTER PREFETCH: the sbias f32x4 loads fed the first QK
// MFMA's C operand at the head of every window with zero latency cover (L2 round
// trip fully exposed, all waves in lockstep). Now window w+1's bias is loaded into
// registers right after window w's QK consumes the current set -> ~500cy of SM+PV
// cover. +~32 VGPR, no LDS/sync changes.
__global__ __launch_bounds__(512, 4) void attn_k(
    const u16* __restrict__ Qb, const u16* __restrict__ Kb, const u16* __restrict__ Vb,
    const float* __restrict__ tmask, const float* __restrict__ sbias,
    const float* __restrict__ zrow, float* __restrict__ out)
{
    __shared__ __align__(16) u16 Ks[2][128 * 64];    // [s_local][d], 8 chunks/row, col^=(row&7)
    __shared__ __align__(16) u16 Vs[2][2][64 * 64];  // [half][d][s_half], 64-u16 rows, col^=(row&7)
    __shared__ __align__(16) u16 Ps[8][16 * 64];     // per-wave P^T half-buffer [t][s_half]

    const int tid  = threadIdx.x;
    const int wid  = tid >> 6;        // 0..7
    const int lane = tid & 63;
    const int ln   = lane & 15;
    const int q    = lane >> 4;

    // XCD-locality swizzle: 512 blocks, 512%8==0 (bijective)
    const int idx   = blockIdx.x;
    const int xcd   = idx & 7;
    const int rest  = idx >> 3;
    const int ttile = rest & 15;               // 16 t-tiles of 128
    const int bh    = (rest >> 4) * 8 + xcd;   // 0..31
    const int b     = bh >> 4;
    const int h     = bh & 15;
    const int t0    = ttile * 128 + wid * 16;

    const u16* Qp = Qb + (size_t)bh * TT * 64;
    const u16* Kp = Kb + (size_t)bh * SS * 64;
    const u16* Vp = Vb + ((size_t)b * CC + h * 64) * SS;

    const float tm = tmask[(size_t)b * TT + t0 + ln];
    const float* bp = (tm > 0.5f) ? (sbias + (size_t)b * SS) : zrow;

    // K staging: 1024 chunks/tile; thread stages slots tid (rows 0..63) and tid+512
    // (rows 64..127). slot -> (r = s>>3, c = s&7), global col = c ^ (r&7).
    const int rk = tid >> 3;
    const int ck = (tid & 7) ^ (rk & 7);
    const u16* kg  = Kp + (size_t)rk * 64 + ck * 8;      // + s0*64 per window
    const u16* kg2 = kg + 64 * 64;                       // rows +64
    // V staging: per half, 512 chunks of 64-u16 rows; thread stages slot tid of each.
    const u16* vg = Vp + (size_t)rk * SS + ck * 8;       // + s0 (+64 for half1)
    const int lws = wid * 512;                           // u16 base per 512-slot region

#define STAGE(buf, sn) do {                                        \
        gload_lds16(kg  + (size_t)(sn) * 64, &Ks[buf][lws]);       \
        gload_lds16(kg2 + (size_t)(sn) * 64, &Ks[buf][4096 + lws]);\
        gload_lds16(vg  + (sn),      &Vs[buf][0][lws]);            \
        gload_lds16(vg  + (sn) + 64, &Vs[buf][1][lws]);            \
    } while (0)

    short8 qB0 = *(const short8*)(Qp + (size_t)(t0 + ln) * 64 + q * 8);
    short8 qB1 = *(const short8*)(Qp + (size_t)(t0 + ln) * 64 + 32 + q * 8);

    float mR = -3.0e38f, lR = 0.f;
    f32x4 oA[4];
#pragma unroll
    for (int dt = 0; dt < 4; dt++) oA[dt] = (f32x4){0.f, 0.f, 0.f, 0.f};

    const int sx0 = ((q ^ (ln & 7)) << 3);
    const int sx1 = (((q + 4) ^ (ln & 7)) << 3);

    u16* pw = Ps[wid];

    STAGE(0, 0);

    // bias prefetch: window 0's C-operands in registers before the loop
    f32x4 bR[8];
#pragma unroll
    for (int nt = 0; nt < 8; nt++)
        bR[nt] = *(const f32x4*)(bp + nt * 16 + q * 4);

    int cur = 0;
#pragma unroll 2
    for (int w = 0; w < 16; ++w) {
        const int s0 = w * 128;
        __syncthreads();
        if (w + 1 < 16) STAGE(cur ^ 1, s0 + 128);

        const u16* KsB = Ks[cur];

        // S^T over 128 s (log2 domain): sc[nt][r] = S^T[nt*16+q*4+r][t=ln]
        f32x4 sc[8];
        __builtin_amdgcn_s_setprio(1);
#pragma unroll
        for (int nt = 0; nt < 8; nt++) {
            const u16* kr = KsB + (nt * 16 + ln) * 64;
            short8 k0 = *(const short8*)(kr + sx0);
            short8 k1 = *(const short8*)(kr + sx1);
            sc[nt] = __builtin_amdgcn_mfma_f32_16x16x32_bf16(k0, qB0, bR[nt], 0, 0, 0);
            sc[nt] = __builtin_amdgcn_mfma_f32_16x16x32_bf16(k1, qB1, sc[nt], 0, 0, 0);
        }
        __builtin_amdgcn_s_setprio(0);

        // reload bias for window w+1 now: SM+PV (~500cy) covers the L2 latency.
        // Tail window re-reads s0 (in-bounds, discarded).
        {
            const int snx = (w + 1 < 16) ? s0 + 128 : s0;
#pragma unroll
            for (int nt = 0; nt < 8; nt++)
                bR[nt] = *(const f32x4*)(bp + snx + nt * 16 + q * 4);
        }

        // row-max over 128 s: in-lane (max3 tree) + xor across the 4 q-groups
        float m4[8];
#pragma unroll
        for (int nt = 0; nt < 8; nt++)
            m4[nt] = fmaxf(max3f(sc[nt][0], sc[nt][1], sc[nt][2]), sc[nt][3]);
        float t1 = max3f(m4[0], m4[1], m4[2]);
        float t2 = max3f(m4[3], m4[4], m4[5]);
        float t3 = fmaxf(m4[6], m4[7]);
        float m_ = max3f(t1, t2, t3);
        m_ = fmaxf(m_, __shfl_xor(m_, 16, 64));
        m_ = fmaxf(m_, __shfl_xor(m_, 32, 64));

        // defer-max (THR=8, log2 domain)
        if (!__all(m_ - mR <= 8.0f)) {
            const float mN = fmaxf(mR, m_);
            const float al = exp2_hw(mR - mN);   // q-uniform per row
            lR *= al;
#pragma unroll
            for (int dt = 0; dt < 4; dt++) oA[dt] *= al;
            mR = mN;
        }

        float ssum = 0.f;
#pragma unroll
        for (int nt = 0; nt < 8; nt++) {
#pragma unroll
            for (int r = 0; r < 4; r++) sc[nt][r] = exp2_hw(sc[nt][r] - mR);
            ssum += (sc[nt][0] + sc[nt][1]) + (sc[nt][2] + sc[nt][3]);
        }
        lR += ssum;   // per-lane partial; merged once at end

        // PV half 0 (s in [s0, s0+64)): P from sc[0..3], V from Vs[cur][0]
#pragma unroll
        for (int nt = 0; nt < 4; nt++) {
            u32x2 wv;
            wv[0] = cvtpk_bf16(sc[nt][0], sc[nt][1]);
            wv[1] = cvtpk_bf16(sc[nt][2], sc[nt][3]);
            const int chunk = (nt << 1) | (q >> 1);
            *(u32x2*)(pw + ln * 64 + ((chunk ^ (ln & 7)) << 3) + ((q & 1) << 2)) = wv;
        }
        {
            const u16* VsH = Vs[cur][0];
            short8 pB0 = *(const short8*)(pw + ln * 64 + sx0);
            short8 pB1 = *(const short8*)(pw + ln * 64 + sx1);
            __builtin_amdgcn_s_setprio(1);
#pragma unroll
            for (int dt = 0; dt < 4; dt++) {
                const u16* vr = VsH + (dt * 16 + ln) * 64;
                short8 v0 = *(const short8*)(vr + sx0);
                short8 v1 = *(const short8*)(vr + sx1);
                oA[dt] = __builtin_amdgcn_mfma_f32_16x16x32_bf16(v0, pB0, oA[dt], 0, 0, 0);
                oA[dt] = __builtin_amdgcn_mfma_f32_16x16x32_bf16(v1, pB1, oA[dt], 0, 0, 0);
            }
            __builtin_amdgcn_s_setprio(0);
        }
        // PV half 1 (s in [s0+64, s0+128)): P from sc[4..7], V from Vs[cur][1]
#pragma unroll
        for (int nt = 0; nt < 4; nt++) {
            u32x2 wv;
            wv[0] = cvtpk_bf16(sc[4 + nt][0], sc[4 + nt][1]);
            wv[1] = cvtpk_bf16(sc[4 + nt][2], sc[4 + nt][3]);
            const int chunk = (nt << 1) | (q >> 1);
            *(u32x2*)(pw + ln * 64 + ((chunk ^ (ln & 7)) << 3) + ((q & 1) << 2)) = wv;
        }
        {
            const u16* VsH = Vs[cur][1];
            short8 pB0 = *(const short8*)(pw + ln * 64 + sx0);
            short8 pB1 = *(const short8*)(pw + ln * 64 + sx1);
            __builtin_amdgcn_s_setprio(1);
#pragma unroll
            for (int dt = 0; dt < 4; dt++) {
                const u16* vr = VsH + (dt * 16 + ln) * 64;
                short8 v0 = *(const short8*)(vr + sx0);
                short8 v1 = *(const short8*)(vr + sx1);
                oA[dt] = __builtin_amdgcn_mfma_f32_16x16x32_bf16(v0, pB0, oA[dt], 0, 0, 0);
                oA[dt] = __builtin_amdgcn_mfma_f32_16x16x32_bf16(v1, pB1, oA[dt], 0, 0, 0);
            }
            __builtin_amdgcn_s_setprio(0);
        }
        cur ^= 1;
    }
#undef STAGE

    // deferred cross-q l-reduce (butterfly over the 4 q-groups of each row)
    lR += __shfl_xor(lR, 16, 64);
    lR += __shfl_xor(lR, 32, 64);
    const float inv = 1.0f / lR;
#pragma unroll
    for (int dt = 0; dt < 4; dt++)
#pragma unroll
        for (int r = 0; r < 4; r++)
            out[((size_t)b * CC + h * 64 + dt * 16 + q * 4 + r) * TT + t0 + ln] =
                oA[dt][r] * inv;
}

extern "C" void kernel_launch(void* const* d_in, const int* in_sizes, int n_in,
                              void* d_out, int out_size, void* d_ws, size_t ws_size,
                              hipStream_t stream)
{
    const float* target = (const float*)d_in[0];
    const float* source = (const float*)d_in[1];
    const float* tmask  = (const float*)d_in[2];
    const float* smask  = (const float*)d_in[3];
    const float* Wq = (const float*)d_in[4];
    const float* bq = (const float*)d_in[5];
    const float* Wk = (const float*)d_in[6];
    const float* bk = (const float*)d_in[7];
    const float* Wv = (const float*)d_in[8];
    const float* bv = (const float*)d_in[9];

    u16* ws = (u16*)d_ws;
    const size_t N1 = (size_t)BB * CC * TT;   // 4,194,304 elements (8 MB bf16)
    u16* Qb = ws;
    u16* Kb = ws + N1;
    u16* Vb = ws + 2 * N1;                    // 24 MB bf16
    float* sbias = (float*)(ws + 3 * N1);     // [2][2048] f32
    float* zrow  = sbias + 2 * SS;            // [2048] f32
    u16* Wb = (u16*)(zrow + SS);              // [3][1024][1024] bf16, 6 MB
    u16* Tt = Wb + 3u * 1048576u;             // [2][2048][1024] bf16, 8 MB
    u16* St = Tt + (size_t)BB * LL * CC;      // [2][2048][1024] bf16, 8 MB

    prep<<<dim3(3584, 1, 1), dim3(256, 1, 1), 0, stream>>>(
        target, source, smask, Wq, Wk, Wv, Wb, Tt, St, sbias, zrow);
    qkv_gemm<<<dim3(192, 1, 1), dim3(512, 1, 1), 0, stream>>>(
        Wb, Tt, St, bq, bk, bv, tmask, Qb, Kb, Vb);
    attn_k<<<dim3(BB*HH*(TT/128), 1, 1), dim3(512, 1, 1), 0, stream>>>(
        Qb, Kb, Vb, tmask, sbias, zrow, (float*)d_out);
}

// Round 11
// 193.666 us; speedup vs baseline: 1.0496x; 1.0496x over previous
//
#include <hip/hip_runtime.h>

#define BB 2
#define CC 1024
#define HH 16
#define TT 2048
#define SS 2048
#define LL 2048   // T == S
#define C2MASK 1442695.0f   // 1e6 * log2(e)

typedef unsigned short u16;
typedef unsigned int u32;
typedef __attribute__((ext_vector_type(8))) short short8;
typedef __attribute__((ext_vector_type(4))) float f32x4;
typedef __attribute__((ext_vector_type(4))) unsigned short us4;
typedef __attribute__((ext_vector_type(2))) unsigned int u32x2;
typedef __attribute__((ext_vector_type(4))) unsigned int u32x4;

__device__ __forceinline__ u16 f2bf(float f) {
    union { float f; unsigned int i; } x; x.f = f;
    unsigned int r = x.i + 0x7FFFu + ((x.i >> 16) & 1u);
    return (u16)(r >> 16);
}
__device__ __forceinline__ float exp2_hw(float x) {
    float r;
    asm("v_exp_f32 %0, %1" : "=v"(r) : "v"(x));
    return r;
}
__device__ __forceinline__ float max3f(float a, float b, float c) {
    float r;
    asm("v_max3_f32 %0, %1, %2, %3" : "=v"(r) : "v"(a), "v"(b), "v"(c));
    return r;
}
__device__ __forceinline__ u32 cvtpk_bf16(float lo, float hi) {
    u32 r;
    asm("v_cvt_pk_bf16_f32 %0, %1, %2" : "=v"(r) : "v"(lo), "v"(hi));
    return r;
}
// direct global->LDS, 16B per lane; LDS dest = wave-uniform base + lane*16
__device__ __forceinline__ void gload_lds16(const u16* g, u16* l) {
    __builtin_amdgcn_global_load_lds(
        (const __attribute__((address_space(1))) unsigned int*)g,
        (__attribute__((address_space(3))) unsigned int*)l, 16, 0, 0);
}

// ---------- prep: one-shot fp32->bf16 conversion (memory-bound, unchanged) ----------
__global__ __launch_bounds__(256) void prep(
    const float* __restrict__ target, const float* __restrict__ source,
    const float* __restrict__ smaskp,
    const float* __restrict__ Wq, const float* __restrict__ Wk, const float* __restrict__ Wv,
    u16* __restrict__ Wb, u16* __restrict__ Tt, u16* __restrict__ St,
    float* __restrict__ sbias, float* __restrict__ zrow)
{
    __shared__ float xs[64][65];   // +1 pad: 2-way (free) banks both phases
    const int tid = threadIdx.x;
    const int bid = blockIdx.x;

    if (bid < 2048) {
        const int img  = bid >> 9;          // 0,1: target b=0,1; 2,3: source b=0,1
        const int tile = bid & 511;
        const int ct = tile >> 5, lt = tile & 31;
        const int c0 = ct * 64, l0 = lt * 64;
        const float* src = ((img < 2) ? target : source) + (size_t)(img & 1) * CC * LL;
        u16* dst = ((img < 2) ? Tt : St) + (size_t)(img & 1) * LL * CC;

        const int i = tid >> 2, seg = (tid & 3) * 16;
        const float* g = src + (size_t)(c0 + i) * LL + l0 + seg;
        f32x4 a0 = *(const f32x4*)g;
        f32x4 a1 = *(const f32x4*)(g + 4);
        f32x4 a2 = *(const f32x4*)(g + 8);
        f32x4 a3 = *(const f32x4*)(g + 12);
#pragma unroll
        for (int j = 0; j < 4; j++) {
            xs[i][seg + j]      = a0[j];
            xs[i][seg + 4 + j]  = a1[j];
            xs[i][seg + 8 + j]  = a2[j];
            xs[i][seg + 12 + j] = a3[j];
        }
        __syncthreads();

        const int l = tid >> 2, cseg = (tid & 3) * 16;
        float f[16];
#pragma unroll
        for (int j = 0; j < 16; j++) f[j] = xs[cseg + j][l];
        u32x4 o0, o1;
#pragma unroll
        for (int k = 0; k < 4; k++) {
            o0[k] = cvtpk_bf16(f[2 * k], f[2 * k + 1]);
            o1[k] = cvtpk_bf16(f[8 + 2 * k], f[9 + 2 * k]);
        }
        u16* d = dst + (size_t)(l0 + l) * CC + c0 + cseg;
        *(u32x4*)d = o0;
        *(u32x4*)(d + 8) = o1;
    } else {
        const int wblk = bid - 2048;              // 0..1535; 512 blocks per matrix
        const size_t idx = (size_t)wblk * 2048 + tid * 8;
        const int m = (int)(idx >> 20);
        const size_t rem = idx & 1048575;
        const float* srcp = ((m == 0) ? Wq : (m == 1) ? Wk : Wv) + rem;
        f32x4 a = *(const f32x4*)srcp;
        f32x4 c = *(const f32x4*)(srcp + 4);
        u32x4 o;
        o[0] = cvtpk_bf16(a[0], a[1]); o[1] = cvtpk_bf16(a[2], a[3]);
        o[2] = cvtpk_bf16(c[0], c[1]); o[3] = cvtpk_bf16(c[2], c[3]);
        *(u32x4*)(Wb + ((size_t)m << 20) + rem) = o;

        if (wblk < 2) {   // fused: s-mask additive bias (log2 domain) + zeros row
            const int b = wblk;
            const float* sm = smaskp + (size_t)b * SS;
            float* sb = sbias + (size_t)b * SS;
            for (int s = tid; s < SS; s += 256) {
                sb[s] = (sm[s] > 0.5f) ? 0.0f : -C2MASK;
                if (b == 0) zrow[s] = 0.0f;
            }
        }
    }
}

// ---------- QKV GEMM: 256x256 tile, BK=64, 8-phase interleave (r7, unchanged) ----------
__global__ __launch_bounds__(512, 2) void qkv_gemm(
    const u16* __restrict__ Wb, const u16* __restrict__ Tt, const u16* __restrict__ St,
    const float* __restrict__ bq, const float* __restrict__ bk, const float* __restrict__ bv,
    const float* __restrict__ tmaskp,
    u16* __restrict__ Qb, u16* __restrict__ Kb, u16* __restrict__ Vb)
{
    __shared__ __align__(16) u16 As[2][16384];   // 256 rows x 64 k, swizzled chunks (32KB ea)
    __shared__ __align__(16) u16 Bs[2][16384];

    // XCD-locality swizzle: 192 blocks, 192%8==0 -> bijective, chunk 24
    const int orig = blockIdx.x;
    const int wg   = (orig & 7) * 24 + (orig >> 3);
    const int mT   = wg >> 4;          // 0..11
    const int nT   = wg & 15;          // 0..15
    const int m0 = mT * 256;           // row in stacked-W space [0,3072)
    const int n0 = nT * 256;           // col in l-space [0,4096)
    const int p  = m0 >> 10;           // 0:Q 1:K 2:V

    const u16* A  = Wb + (size_t)m0 * CC;
    const u16* Bx = ((p == 0) ? Tt : St) + (size_t)n0 * CC;
    const float* bias = (p == 0) ? bq : (p == 1) ? bk : bv;

    const int tid  = threadIdx.x;
    const int lane = tid & 63;
    const int wid  = tid >> 6;         // 0..7
    const int ln   = lane & 15;
    const int q    = lane >> 4;
    const int wm   = (wid >> 2) * 128; // 2 M-groups
    const int wn   = (wid & 3) * 64;   // 4 N-groups

    const u16* ag[4]; const u16* bg[4];
#pragma unroll
    for (int e = 0; e < 4; e++) {
        const int s = tid + e * 512;
        const int row = s >> 3;
        const int c = (s & 7) ^ (row & 7);
        ag[e] = A  + (size_t)row * CC + c * 8;
        bg[e] = Bx + (size_t)row * CC + c * 8;
    }
    const int lw = wid * 512;          // wave-uniform u16 LDS base within each 512-slot set

#define STG_A(buf, k0, e)  gload_lds16(ag[e] + (k0), &As[buf][(e) * 4096 + lw])
#define STG_B(buf, k0, e)  gload_lds16(bg[e] + (k0), &Bs[buf][(e) * 4096 + lw])

    f32x4 acc[8][4];
#pragma unroll
    for (int i = 0; i < 8; i++)
#pragma unroll
        for (int j = 0; j < 4; j++) acc[i][j] = (f32x4){0.f, 0.f, 0.f, 0.f};

    const int sx0 = ((q ^ (ln & 7)) << 3);
    const int sx1 = (((q + 4) ^ (ln & 7)) << 3);

    short8 aQ[4][2];        // current A-quadrant
    short8 bQ[2][2][2];     // both B-quadrants [ntg][nti][kk]

#define PH_READ_A(cb, base_mt) do {                                        \
    _Pragma("unroll") for (int mt = 0; mt < 4; mt++) {                     \
        const u16* ar = &As[cb][(wm + ((base_mt) + mt) * 16 + ln) * 64];   \
        aQ[mt][0] = *(const short8*)(ar + sx0);                            \
        aQ[mt][1] = *(const short8*)(ar + sx1); } } while (0)
#define PH_READ_B(cb, ntg) do {                                            \
    _Pragma("unroll") for (int nt = 0; nt < 2; nt++) {                     \
        const u16* br = &Bs[cb][(wn + ((ntg) * 2 + nt) * 16 + ln) * 64];   \
        bQ[ntg][nt][0] = *(const short8*)(br + sx0);                       \
        bQ[ntg][nt][1] = *(const short8*)(br + sx1); } } while (0)
#define PH_MFMA(mbase, ntg) do {                                           \
    __builtin_amdgcn_s_setprio(1);                                         \
    _Pragma("unroll") for (int mt = 0; mt < 4; mt++)                       \
    _Pragma("unroll") for (int nt = 0; nt < 2; nt++) {                     \
        acc[(mbase) + mt][(ntg) * 2 + nt] = __builtin_amdgcn_mfma_f32_16x16x32_bf16( \
            aQ[mt][0], bQ[ntg][nt][0], acc[(mbase) + mt][(ntg) * 2 + nt], 0, 0, 0);  \
        acc[(mbase) + mt][(ntg) * 2 + nt] = __builtin_amdgcn_mfma_f32_16x16x32_bf16( \
            aQ[mt][1], bQ[ntg][nt][1], acc[(mbase) + mt][(ntg) * 2 + nt], 0, 0, 0); } \
    __builtin_amdgcn_s_setprio(0); } while (0)
#define LGKM0 do { asm volatile("s_waitcnt lgkmcnt(0)" ::: "memory");      \
                   __builtin_amdgcn_sched_barrier(0); } while (0)
#define VMDRAIN do { asm volatile("s_waitcnt vmcnt(0)" ::: "memory");      \
                     __builtin_amdgcn_sched_barrier(0); } while (0)

    // prologue: tile 0 -> buf0; __syncthreads drains vmcnt and publishes it
    STG_A(0, 0, 0); STG_A(0, 0, 1); STG_A(0, 0, 2); STG_A(0, 0, 3);
    STG_B(0, 0, 0); STG_B(0, 0, 1); STG_B(0, 0, 2); STG_B(0, 0, 3);
    __syncthreads();

#pragma unroll 1
    for (int T = 0; T < 16; ++T) {
        const int c  = T & 1;
        const int kn = (T + 1) * 64;
        const bool stg = (T < 15);

        // ph0: A-quad0 + B-quad0 | stage next-tile A
        PH_READ_A(c, 0); PH_READ_B(c, 0);
        if (stg) { STG_A(c ^ 1, kn, 0); STG_A(c ^ 1, kn, 1);
                   STG_A(c ^ 1, kn, 2); STG_A(c ^ 1, kn, 3); }
        __builtin_amdgcn_s_barrier(); LGKM0; PH_MFMA(0, 0);
        __builtin_amdgcn_s_barrier();

        // ph1: B-quad1 | stage next-tile B
        PH_READ_B(c, 1);
        if (stg) { STG_B(c ^ 1, kn, 0); STG_B(c ^ 1, kn, 1);
                   STG_B(c ^ 1, kn, 2); STG_B(c ^ 1, kn, 3); }
        __builtin_amdgcn_s_barrier(); LGKM0; PH_MFMA(0, 1);
        __builtin_amdgcn_s_barrier();

        // ph2: A-quad1
        PH_READ_A(c, 4);
        __builtin_amdgcn_s_barrier(); LGKM0; PH_MFMA(4, 0);
        __builtin_amdgcn_s_barrier();

        // ph3: pure MFMA; then race-free gate BEFORE the closing barrier
        PH_MFMA(4, 1);
        VMDRAIN;
        __builtin_amdgcn_s_barrier();
    }
#undef VMDRAIN
#undef LGKM0
#undef PH_MFMA
#undef PH_READ_B
#undef PH_READ_A
#undef STG_B
#undef STG_A

    // Q folds 1/sqrt(DH)*log2e and tmask (zeroed rows -> uniform softmax in attn)
    const float oscale = 0.18033688011112042f;
    // D layout: col = lane&15 (= l), row = q*4+reg (= o)
#pragma unroll
    for (int mt = 0; mt < 8; mt++) {
        const int o_base = (m0 & 1023) + wm + mt * 16 + q * 4;   // within-p output row
        float bsf[4];
#pragma unroll
        for (int r = 0; r < 4; r++) bsf[r] = bias[o_base + r];
#pragma unroll
        for (int nt = 0; nt < 4; nt++) {
            const int l  = n0 + wn + nt * 16 + ln;   // 0..4095
            const int b  = l >> 11;
            const int tk = l & 2047;
            if (p == 2) {
#pragma unroll
                for (int r = 0; r < 4; r++)
                    Vb[((size_t)b * CC + o_base + r) * SS + tk] = f2bf(acc[mt][nt][r] + bsf[r]);
            } else {
                const int h = o_base >> 6;
                const int d = o_base & 63;
                u16* dst = (p == 0) ? Qb : Kb;
                float sc2 = 1.0f;
                if (p == 0) sc2 = oscale * tmaskp[(size_t)b * TT + tk];
                us4 pk;
#pragma unroll
                for (int r = 0; r < 4; r++) pk[r] = (u16)f2bf((acc[mt][nt][r] + bsf[r]) * sc2);
                *(us4*)(dst + ((size_t)(b * HH + h) * TT + tk) * 64 + d) = pk;
            }
        }
    }
}

// ---------- flash attention: 8 waves, t=128/block, KVBLK=128, V halves ----------
// r9 structure (bias prefetch REVERTED: r10 showed +32-VGPR prefetch caused scratch
// spill traffic, +11MB writes/dispatch, +6.8us). One new change: P-path reorder —
// both halves' P packed+written+read BEFORE the h0 MFMA cluster, so the h1 LDS
// round-trip (~240cy lgkm) hides under PV-h0's MFMAs. Per-wave DS ordering makes
// this safe (read-h0 issued before write-h1 reads pre-h1 data). +8 VGPR only.
__global__ __launch_bounds__(512, 4) void attn_k(
    const u16* __restrict__ Qb, const u16* __restrict__ Kb, const u16* __restrict__ Vb,
    const float* __restrict__ tmask, const float* __restrict__ sbias,
    const float* __restrict__ zrow, float* __restrict__ out)
{
    __shared__ __align__(16) u16 Ks[2][128 * 64];    // [s_local][d], 8 chunks/row, col^=(row&7)
    __shared__ __align__(16) u16 Vs[2][2][64 * 64];  // [half][d][s_half], 64-u16 rows, col^=(row&7)
    __shared__ __align__(16) u16 Ps[8][16 * 64];     // per-wave P^T half-buffer [t][s_half]

    const int tid  = threadIdx.x;
    const int wid  = tid >> 6;        // 0..7
    const int lane = tid & 63;
    const int ln   = lane & 15;
    const int q    = lane >> 4;

    // XCD-locality swizzle: 512 blocks, 512%8==0 (bijective)
    const int idx   = blockIdx.x;
    const int xcd   = idx & 7;
    const int rest  = idx >> 3;
    const int ttile = rest & 15;               // 16 t-tiles of 128
    const int bh    = (rest >> 4) * 8 + xcd;   // 0..31
    const int b     = bh >> 4;
    const int h     = bh & 15;
    const int t0    = ttile * 128 + wid * 16;

    const u16* Qp = Qb + (size_t)bh * TT * 64;
    const u16* Kp = Kb + (size_t)bh * SS * 64;
    const u16* Vp = Vb + ((size_t)b * CC + h * 64) * SS;

    const float tm = tmask[(size_t)b * TT + t0 + ln];
    const float* bp = (tm > 0.5f) ? (sbias + (size_t)b * SS) : zrow;

    // K staging: 1024 chunks/tile; thread stages slots tid (rows 0..63) and tid+512
    // (rows 64..127). slot -> (r = s>>3, c = s&7), global col = c ^ (r&7).
    const int rk = tid >> 3;
    const int ck = (tid & 7) ^ (rk & 7);
    const u16* kg  = Kp + (size_t)rk * 64 + ck * 8;      // + s0*64 per window
    const u16* kg2 = kg + 64 * 64;                       // rows +64
    // V staging: per half, 512 chunks of 64-u16 rows; thread stages slot tid of each.
    const u16* vg = Vp + (size_t)rk * SS + ck * 8;       // + s0 (+64 for half1)
    const int lws = wid * 512;                           // u16 base per 512-slot region

#define STAGE(buf, sn) do {                                        \
        gload_lds16(kg  + (size_t)(sn) * 64, &Ks[buf][lws]);       \
        gload_lds16(kg2 + (size_t)(sn) * 64, &Ks[buf][4096 + lws]);\
        gload_lds16(vg  + (sn),      &Vs[buf][0][lws]);            \
        gload_lds16(vg  + (sn) + 64, &Vs[buf][1][lws]);            \
    } while (0)

    short8 qB0 = *(const short8*)(Qp + (size_t)(t0 + ln) * 64 + q * 8);
    short8 qB1 = *(const short8*)(Qp + (size_t)(t0 + ln) * 64 + 32 + q * 8);

    float mR = -3.0e38f, lR = 0.f;
    f32x4 oA[4];
#pragma unroll
    for (int dt = 0; dt < 4; dt++) oA[dt] = (f32x4){0.f, 0.f, 0.f, 0.f};

    const int sx0 = ((q ^ (ln & 7)) << 3);
    const int sx1 = (((q + 4) ^ (ln & 7)) << 3);

    u16* pw = Ps[wid];

    STAGE(0, 0);

    int cur = 0;
#pragma unroll 2
    for (int w = 0; w < 16; ++w) {
        const int s0 = w * 128;
        __syncthreads();
        if (w + 1 < 16) STAGE(cur ^ 1, s0 + 128);

        const u16* KsB = Ks[cur];

        // S^T over 128 s (log2 domain): sc[nt][r] = S^T[nt*16+q*4+r][t=ln]
        f32x4 sc[8];
        __builtin_amdgcn_s_setprio(1);
#pragma unroll
        for (int nt = 0; nt < 8; nt++) {
            const u16* kr = KsB + (nt * 16 + ln) * 64;
            short8 k0 = *(const short8*)(kr + sx0);
            short8 k1 = *(const short8*)(kr + sx1);
            f32x4 bias = *(const f32x4*)(bp + s0 + nt * 16 + q * 4);
            sc[nt] = __builtin_amdgcn_mfma_f32_16x16x32_bf16(k0, qB0, bias, 0, 0, 0);
            sc[nt] = __builtin_amdgcn_mfma_f32_16x16x32_bf16(k1, qB1, sc[nt], 0, 0, 0);
        }
        __builtin_amdgcn_s_setprio(0);

        // row-max over 128 s: in-lane (max3 tree) + xor across the 4 q-groups
        float m4[8];
#pragma unroll
        for (int nt = 0; nt < 8; nt++)
            m4[nt] = fmaxf(max3f(sc[nt][0], sc[nt][1], sc[nt][2]), sc[nt][3]);
        float t1 = max3f(m4[0], m4[1], m4[2]);
        float t2 = max3f(m4[3], m4[4], m4[5]);
        float t3 = fmaxf(m4[6], m4[7]);
        float m_ = max3f(t1, t2, t3);
        m_ = fmaxf(m_, __shfl_xor(m_, 16, 64));
        m_ = fmaxf(m_, __shfl_xor(m_, 32, 64));

        // defer-max (THR=8, log2 domain)
        if (!__all(m_ - mR <= 8.0f)) {
            const float mN = fmaxf(mR, m_);
            const float al = exp2_hw(mR - mN);   // q-uniform per row
            lR *= al;
#pragma unroll
            for (int dt = 0; dt < 4; dt++) oA[dt] *= al;
            mR = mN;
        }

        float ssum = 0.f;
#pragma unroll
        for (int nt = 0; nt < 8; nt++) {
#pragma unroll
            for (int r = 0; r < 4; r++) sc[nt][r] = exp2_hw(sc[nt][r] - mR);
            ssum += (sc[nt][0] + sc[nt][1]) + (sc[nt][2] + sc[nt][3]);
        }
        lR += ssum;   // per-lane partial; merged once at end

        // P-path reorder: pack/write/read BOTH halves before the h0 MFMA cluster.
        // DS ops are in-order per wave: read-h0 (issued before write-h1) reads h0
        // data; read-h1 follows write-h1. h1's LDS round-trip hides under PV-h0.
#pragma unroll
        for (int nt = 0; nt < 4; nt++) {
            u32x2 wv;
            wv[0] = cvtpk_bf16(sc[nt][0], sc[nt][1]);
            wv[1] = cvtpk_bf16(sc[nt][2], sc[nt][3]);
            const int chunk = (nt << 1) | (q >> 1);
            *(u32x2*)(pw + ln * 64 + ((chunk ^ (ln & 7)) << 3) + ((q & 1) << 2)) = wv;
        }
        short8 pB0h0 = *(const short8*)(pw + ln * 64 + sx0);
        short8 pB1h0 = *(const short8*)(pw + ln * 64 + sx1);
#pragma unroll
        for (int nt = 0; nt < 4; nt++) {
            u32x2 wv;
            wv[0] = cvtpk_bf16(sc[4 + nt][0], sc[4 + nt][1]);
            wv[1] = cvtpk_bf16(sc[4 + nt][2], sc[4 + nt][3]);
            const int chunk = (nt << 1) | (q >> 1);
            *(u32x2*)(pw + ln * 64 + ((chunk ^ (ln & 7)) << 3) + ((q & 1) << 2)) = wv;
        }
        short8 pB0h1 = *(const short8*)(pw + ln * 64 + sx0);
        short8 pB1h1 = *(const short8*)(pw + ln * 64 + sx1);

        // PV half 0 (s in [s0, s0+64)): V from Vs[cur][0]
        {
            const u16* VsH = Vs[cur][0];
            __builtin_amdgcn_s_setprio(1);
#pragma unroll
            for (int dt = 0; dt < 4; dt++) {
                const u16* vr = VsH + (dt * 16 + ln) * 64;
                short8 v0 = *(const short8*)(vr + sx0);
                short8 v1 = *(const short8*)(vr + sx1);
                oA[dt] = __builtin_amdgcn_mfma_f32_16x16x32_bf16(v0, pB0h0, oA[dt], 0, 0, 0);
                oA[dt] = __builtin_amdgcn_mfma_f32_16x16x32_bf16(v1, pB1h0, oA[dt], 0, 0, 0);
            }
            __builtin_amdgcn_s_setprio(0);
        }
        // PV half 1 (s in [s0+64, s0+128)): V from Vs[cur][1]
        {
            const u16* VsH = Vs[cur][1];
            __builtin_amdgcn_s_setprio(1);
#pragma unroll
            for (int dt = 0; dt < 4; dt++) {
                const u16* vr = VsH + (dt * 16 + ln) * 64;
                short8 v0 = *(const short8*)(vr + sx0);
                short8 v1 = *(const short8*)(vr + sx1);
                oA[dt] = __builtin_amdgcn_mfma_f32_16x16x32_bf16(v0, pB0h1, oA[dt], 0, 0, 0);
                oA[dt] = __builtin_amdgcn_mfma_f32_16x16x32_bf16(v1, pB1h1, oA[dt], 0, 0, 0);
            }
            __builtin_amdgcn_s_setprio(0);
        }
        cur ^= 1;
    }
#undef STAGE

    // deferred cross-q l-reduce (butterfly over the 4 q-groups of each row)
    lR += __shfl_xor(lR, 16, 64);
    lR += __shfl_xor(lR, 32, 64);
    const float inv = 1.0f / lR;
#pragma unroll
    for (int dt = 0; dt < 4; dt++)
#pragma unroll
        for (int r = 0; r < 4; r++)
            out[((size_t)b * CC + h * 64 + dt * 16 + q * 4 + r) * TT + t0 + ln] =
                oA[dt][r] * inv;
}

extern "C" void kernel_launch(void* const* d_in, const int* in_sizes, int n_in,
                              void* d_out, int out_size, void* d_ws, size_t ws_size,
                              hipStream_t stream)
{
    const float* target = (const float*)d_in[0];
    const float* source = (const float*)d_in[1];
    const float* tmask  = (const float*)d_in[2];
    const float* smask  = (const float*)d_in[3];
    const float* Wq = (const float*)d_in[4];
    const float* bq = (const float*)d_in[5];
    const float* Wk = (const float*)d_in[6];
    const float* bk = (const float*)d_in[7];
    const float* Wv = (const float*)d_in[8];
    const float* bv = (const float*)d_in[9];

    u16* ws = (u16*)d_ws;
    const size_t N1 = (size_t)BB * CC * TT;   // 4,194,304 elements (8 MB bf16)
    u16* Qb = ws;
    u16* Kb = ws + N1;
    u16* Vb = ws + 2 * N1;                    // 24 MB bf16
    float* sbias = (float*)(ws + 3 * N1);     // [2][2048] f32
    float* zrow  = sbias + 2 * SS;            // [2048] f32
    u16* Wb = (u16*)(zrow + SS);              // [3][1024][1024] bf16, 6 MB
    u16* Tt = Wb + 3u * 1048576u;             // [2][2048][1024] bf16, 8 MB
    u16* St = Tt + (size_t)BB * LL * CC;      // [2][2048][1024] bf16, 8 MB

    prep<<<dim3(3584, 1, 1), dim3(256, 1, 1), 0, stream>>>(
        target, source, smask, Wq, Wk, Wv, Wb, Tt, St, sbias, zrow);
    qkv_gemm<<<dim3(192, 1, 1), dim3(512, 1, 1), 0, stream>>>(
        Wb, Tt, St, bq, bk, bv, tmask, Qb, Kb, Vb);
    attn_k<<<dim3(BB*HH*(TT/128), 1, 1), dim3(512, 1, 1), 0, stream>>>(
        Qb, Kb, Vb, tmask, sbias, zrow, (float*)d_out);
}